// Round 3
// baseline (230.186 us; speedup 1.0000x reference)
//
#include <hip/hip_runtime.h>
#include <hip/hip_bf16.h>
#include <math.h>

// Problem constants (from reference setup_inputs)
constexpr int B = 4, S = 10, N = 2048, D = 128;

constexpr int KS      = 8;              // database slices per (b,s,dir)
constexpr int SLICE   = N / KS;         // 256 db points per block
constexpr int THREADS = 128;            // 2 waves per block
constexpr int QPT     = N / THREADS;    // 16 queries per thread
constexpr int CHAM_BLOCKS = B * S * 2 * KS;   // 640
constexpr int TEMP_BLOCKS = 16;
constexpr int KL_BLOCKS   = 1;
constexpr int TOTAL_BLOCKS = CHAM_BLOCKS + TEMP_BLOCKS + KL_BLOCKS;  // 657
constexpr int TOTQ    = B * S * 2 * N;        // 163840 (query, dir) pairs
constexpr int TEMP_ELEMS = B * (S - 1) * N;   // 73728
constexpr int TEMP_PER_BLOCK = TEMP_ELEMS / TEMP_BLOCKS;  // 4608 = 36*128
constexpr int KL_ELEMS = B * S * D;           // 5120 = 40*128

// ws layout: [0 .. KS*TOTQ) float d^2 partials, then control block
struct Ctl {
    unsigned arrive;   // phase-1 barrier counter
    unsigned done;     // phase-2 ticket counter
    float    chamsum;
    float    tempsum;
    float    klsum;
};
constexpr size_t WS_CTL = (size_t)KS * TOTQ;   // float offset of Ctl

typedef float v2f __attribute__((ext_vector_type(2)));

__device__ __forceinline__ v2f pk_fma(v2f a, v2f b, v2f c) {
    v2f d;
    asm("v_pk_fma_f32 %0, %1, %2, %3" : "=v"(d) : "v"(a), "v"(b), "v"(c));
    return d;
}

// result valid on ALL threads (128-thread block, 2 waves)
__device__ __forceinline__ float block_sum(float v, float* red) {
    #pragma unroll
    for (int off = 32; off > 0; off >>= 1)
        v += __shfl_down(v, off, 64);
    if ((threadIdx.x & 63) == 0) red[threadIdx.x >> 6] = v;
    __syncthreads();
    return red[0] + red[1];
}

__global__ __launch_bounds__(THREADS) void fused_kernel(
        const float* __restrict__ pred, const float* __restrict__ tgt,
        const float* __restrict__ prior_mean, const float* __restrict__ prior_lv,
        const float* __restrict__ post_mean,  const float* __restrict__ post_lv,
        float* __restrict__ ws, float* __restrict__ out) {
    __shared__ float4 db[SLICE];   // [2p]={x0,x1,y0,y1} [2p+1]={z0,z1,m0,m1}, m=-0.5|g|^2
    __shared__ float red[2];

    const int bid = blockIdx.x;
    const int tid = threadIdx.x;
    Ctl* ctl = (Ctl*)(ws + WS_CTL);

    // ---------------- Phase 1 ----------------
    if (bid < CHAM_BLOCKS) {
        const int ks  = bid & (KS - 1);
        const int dir = (bid >> 3) & 1;
        const int bs  = bid >> 4;                 // b*S + s
        const float* qb  = (dir ? tgt : pred) + (size_t)bs * N * 3;  // queries
        const float* dbp = (dir ? pred : tgt) + (size_t)bs * N * 3;  // database

        // stage 256 db points (1 pair per thread), pair-interleaved
        {
            const int p0 = ks * SLICE + 2 * tid;
            const float x0 = dbp[3 * p0 + 0], y0 = dbp[3 * p0 + 1], z0 = dbp[3 * p0 + 2];
            const float x1 = dbp[3 * p0 + 3], y1 = dbp[3 * p0 + 4], z1 = dbp[3 * p0 + 5];
            db[2 * tid + 0] = make_float4(x0, x1, y0, y1);
            db[2 * tid + 1] = make_float4(z0, z1,
                                          -0.5f * (x0 * x0 + y0 * y0 + z0 * z0),
                                          -0.5f * (x1 * x1 + y1 * y1 + z1 * z1));
        }

        // 16 queries per thread, splatted for packed fma
        v2f px2[QPT], py2[QPT], pz2[QPT];
        float acc[QPT];
        #pragma unroll
        for (int i = 0; i < QPT; ++i) {
            const int q = tid + THREADS * i;
            const float x = qb[3 * q + 0], y = qb[3 * q + 1], z = qb[3 * q + 2];
            px2[i] = (v2f){x, x};
            py2[i] = (v2f){y, y};
            pz2[i] = (v2f){z, z};
            acc[i] = -1e30f;
        }
        __syncthreads();

        // max over slice of score = p.g - 0.5|g|^2 (2 db points per packed op)
        #pragma unroll 2
        for (int p = 0; p < SLICE / 2; ++p) {
            const float4 Axy = db[2 * p + 0];
            const float4 Bzm = db[2 * p + 1];
            const v2f x01 = (v2f){Axy.x, Axy.y};
            const v2f y01 = (v2f){Axy.z, Axy.w};
            const v2f z01 = (v2f){Bzm.x, Bzm.y};
            const v2f m01 = (v2f){Bzm.z, Bzm.w};
            #pragma unroll
            for (int i = 0; i < QPT; ++i) {
                v2f t = pk_fma(pz2[i], z01, m01);
                t = pk_fma(py2[i], y01, t);
                t = pk_fma(px2[i], x01, t);
                acc[i] = fmaxf(acc[i], fmaxf(t.x, t.y));   // v_max3_f32
            }
        }

        // partial d^2 for this slice
        float* part = ws + (size_t)ks * TOTQ + (size_t)(bs * 2 + dir) * N;
        #pragma unroll
        for (int i = 0; i < QPT; ++i) {
            const float x = px2[i].x, y = py2[i].x, z = pz2[i].x;
            const float pn = x * x + y * y + z * z;
            part[tid + THREADS * i] = pn - 2.0f * acc[i];
        }
    } else if (bid < CHAM_BLOCKS + TEMP_BLOCKS) {
        const int tb = bid - CHAM_BLOCKS;
        float s = 0.0f;
        for (int it = 0; it < TEMP_PER_BLOCK / THREADS; ++it) {
            const int i = tb * TEMP_PER_BLOCK + it * THREADS + tid;
            const int b = i / ((S - 1) * N);
            const int r = i % ((S - 1) * N);
            const float* p0 = pred + (size_t)(b * S * N + r) * 3;
            const float* p1 = p0 + (size_t)N * 3;
            const float dx = p1[0] - p0[0];
            const float dy = p1[1] - p0[1];
            const float dz = p1[2] - p0[2];
            s += sqrtf(dx * dx + dy * dy + dz * dz);
        }
        const float tot = block_sum(s, red);
        if (tid == 0) atomicAdd(&ctl->tempsum, tot);
    } else {
        float s = 0.0f;
        for (int it = 0; it < KL_ELEMS / THREADS; ++it) {
            const int i = it * THREADS + tid;
            const float a  = prior_lv[i];
            const float bb = post_lv[i];
            const float dm = post_mean[i] - prior_mean[i];
            s += a - bb + (expf(bb) + dm * dm) * expf(-a) - 1.0f;
        }
        const float tot = block_sum(s, red);
        if (tid == 0) atomicAdd(&ctl->klsum, tot);
    }

    // ---------------- grid barrier (device scope) ----------------
    __syncthreads();
    __threadfence();   // release: drain + L2 writeback
    if (tid == 0) {
        __hip_atomic_fetch_add(&ctl->arrive, 1u, __ATOMIC_RELEASE, __HIP_MEMORY_SCOPE_AGENT);
        while (__hip_atomic_load(&ctl->arrive, __ATOMIC_ACQUIRE, __HIP_MEMORY_SCOPE_AGENT)
               < (unsigned)TOTAL_BLOCKS)
            __builtin_amdgcn_s_sleep(8);
    }
    __syncthreads();
    __threadfence();   // acquire: invalidate stale L1/L2 lines

    // ---------------- Phase 2: min over slices, sqrt, sum ----------------
    if (bid < CHAM_BLOCKS) {
        float ssum = 0.0f;
        #pragma unroll
        for (int r = 0; r < 2; ++r) {
            const int u = bid * 256 + r * THREADS + tid;   // 640*256 = TOTQ
            float d2 = ws[u];
            #pragma unroll
            for (int k = 1; k < KS; ++k)
                d2 = fminf(d2, ws[(size_t)k * TOTQ + u]);
            ssum += sqrtf(fmaxf(d2, 0.0f));
        }
        __syncthreads();   // red[] reuse safety
        const float tot = block_sum(ssum, red);
        if (tid == 0) {
            atomicAdd(&ctl->chamsum, tot);
            __threadfence();
            const unsigned ticket =
                __hip_atomic_fetch_add(&ctl->done, 1u, __ATOMIC_ACQ_REL, __HIP_MEMORY_SCOPE_AGENT);
            if (ticket == CHAM_BLOCKS - 1) {
                const float recon    = __hip_atomic_load(&ctl->chamsum, __ATOMIC_ACQUIRE,
                                                         __HIP_MEMORY_SCOPE_AGENT) / (float)(B * S * N);
                const float kl       = 0.5f * ctl->klsum / (float)(B * S);
                const float temporal = ctl->tempsum / (float)TEMP_ELEMS;
                out[0] = recon + kl + 0.1f * temporal;
                out[1] = recon;
                out[2] = kl;
                out[3] = temporal;
                out[4] = 0.0f;
            }
        }
    }
}

extern "C" void kernel_launch(void* const* d_in, const int* in_sizes, int n_in,
                              void* d_out, int out_size, void* d_ws, size_t ws_size,
                              hipStream_t stream) {
    const float* pred = (const float*)d_in[0];
    const float* tgt  = (const float*)d_in[1];
    const float* pm   = (const float*)d_in[2];
    const float* plv  = (const float*)d_in[3];
    const float* qm   = (const float*)d_in[4];
    const float* qlv  = (const float*)d_in[5];
    float* out = (float*)d_out;
    float* ws  = (float*)d_ws;

    // zero the control block (counters + accumulators)
    hipMemsetAsync(ws + WS_CTL, 0, sizeof(Ctl), stream);

    fused_kernel<<<TOTAL_BLOCKS, THREADS, 0, stream>>>(
        pred, tgt, pm, plv, qm, qlv, ws, out);
}

// Round 4
// 123.424 us; speedup vs baseline: 1.8650x; 1.8650x over previous
//
#include <hip/hip_runtime.h>
#include <hip/hip_bf16.h>
#include <math.h>

// Problem constants (from reference setup_inputs)
constexpr int B = 4, S = 10, N = 2048, D = 128;

constexpr int KS      = 8;              // database slices per (b,s,dir)
constexpr int SLICE   = N / KS;         // 256 db points per block
constexpr int THREADS = 128;            // 2 waves per block
constexpr int QPT     = N / THREADS;    // 16 queries per thread
constexpr int CHAM_BLOCKS = B * S * 2 * KS;   // 640
constexpr int TEMP_BLOCKS = 16;
constexpr int TOTAL_BLOCKS = CHAM_BLOCKS + TEMP_BLOCKS + 1;  // 657
constexpr int TOTQ    = B * S * 2 * N;        // 163840 (query, dir) pairs
constexpr int TEMP_ELEMS = B * (S - 1) * N;   // 73728
constexpr int TEMP_PER_BLOCK = TEMP_ELEMS / TEMP_BLOCKS;  // 4608 = 36*128
constexpr int KL_ELEMS = B * S * D;           // 5120 = 40*128

// ws layout (floats):
//   [0 .. KS*TOTQ)             partial d^2 per (slice, query)
//   [WS_CHSUM .. +640)         per-block chamfer sums (k2)
//   [WS_TPART .. +16)          temporal block sums
//   [WS_KL]                    kl sum
constexpr size_t WS_CHSUM = (size_t)KS * TOTQ;
constexpr size_t WS_TPART = WS_CHSUM + TOTQ / 256;
constexpr size_t WS_KL    = WS_TPART + TEMP_BLOCKS;

typedef float v2f __attribute__((ext_vector_type(2)));

__device__ __forceinline__ v2f pk_fma(v2f a, v2f b, v2f c) {
    v2f d;
    asm("v_pk_fma_f32 %0, %1, %2, %3" : "=v"(d) : "v"(a), "v"(b), "v"(c));
    return d;
}

// result valid on thread 0 (128-thread block, 2 waves)
__device__ __forceinline__ float block_sum(float v, float* red) {
    #pragma unroll
    for (int off = 32; off > 0; off >>= 1)
        v += __shfl_down(v, off, 64);
    if ((threadIdx.x & 63) == 0) red[threadIdx.x >> 6] = v;
    __syncthreads();
    return red[0] + red[1];
}

// ---------------------------------------------------------------------------
// K1: blocks [0,640): chamfer d^2 partials; [640,656): temporal; 656: kl
// ---------------------------------------------------------------------------
__global__ __launch_bounds__(THREADS) void k1_kernel(
        const float* __restrict__ pred, const float* __restrict__ tgt,
        const float* __restrict__ prior_mean, const float* __restrict__ prior_lv,
        const float* __restrict__ post_mean,  const float* __restrict__ post_lv,
        float* __restrict__ ws) {
    __shared__ float4 db[SLICE];   // [2p]={x0,x1,y0,y1} [2p+1]={z0,z1,m0,m1}, m=-0.5|g|^2
    __shared__ float red[2];

    const int bid = blockIdx.x;
    const int tid = threadIdx.x;

    if (bid < CHAM_BLOCKS) {
        const int ks  = bid & (KS - 1);
        const int dir = (bid >> 3) & 1;
        const int bs  = bid >> 4;                 // b*S + s
        const float* qb  = (dir ? tgt : pred) + (size_t)bs * N * 3;  // queries
        const float* dbp = (dir ? pred : tgt) + (size_t)bs * N * 3;  // database

        // stage 256 db points (1 pair per thread), pair-interleaved
        {
            const int p0 = ks * SLICE + 2 * tid;
            const float x0 = dbp[3 * p0 + 0], y0 = dbp[3 * p0 + 1], z0 = dbp[3 * p0 + 2];
            const float x1 = dbp[3 * p0 + 3], y1 = dbp[3 * p0 + 4], z1 = dbp[3 * p0 + 5];
            db[2 * tid + 0] = make_float4(x0, x1, y0, y1);
            db[2 * tid + 1] = make_float4(z0, z1,
                                          -0.5f * (x0 * x0 + y0 * y0 + z0 * z0),
                                          -0.5f * (x1 * x1 + y1 * y1 + z1 * z1));
        }

        // 16 queries per thread, splatted for packed fma
        v2f px2[QPT], py2[QPT], pz2[QPT];
        float acc[QPT];
        #pragma unroll
        for (int i = 0; i < QPT; ++i) {
            const int q = tid + THREADS * i;
            const float x = qb[3 * q + 0], y = qb[3 * q + 1], z = qb[3 * q + 2];
            px2[i] = (v2f){x, x};
            py2[i] = (v2f){y, y};
            pz2[i] = (v2f){z, z};
            acc[i] = -1e30f;
        }
        __syncthreads();

        // max over slice of score = p.g - 0.5|g|^2 (2 db points per packed op)
        #pragma unroll 2
        for (int p = 0; p < SLICE / 2; ++p) {
            const float4 Axy = db[2 * p + 0];
            const float4 Bzm = db[2 * p + 1];
            const v2f x01 = (v2f){Axy.x, Axy.y};
            const v2f y01 = (v2f){Axy.z, Axy.w};
            const v2f z01 = (v2f){Bzm.x, Bzm.y};
            const v2f m01 = (v2f){Bzm.z, Bzm.w};
            #pragma unroll
            for (int i = 0; i < QPT; ++i) {
                v2f t = pk_fma(pz2[i], z01, m01);
                t = pk_fma(py2[i], y01, t);
                t = pk_fma(px2[i], x01, t);
                acc[i] = fmaxf(acc[i], fmaxf(t.x, t.y));   // v_max3_f32
            }
        }

        // partial d^2 for this slice
        float* part = ws + (size_t)ks * TOTQ + (size_t)(bs * 2 + dir) * N;
        #pragma unroll
        for (int i = 0; i < QPT; ++i) {
            const float x = px2[i].x, y = py2[i].x, z = pz2[i].x;
            const float pn = x * x + y * y + z * z;
            part[tid + THREADS * i] = pn - 2.0f * acc[i];
        }
    } else if (bid < CHAM_BLOCKS + TEMP_BLOCKS) {
        const int tb = bid - CHAM_BLOCKS;
        float s = 0.0f;
        for (int it = 0; it < TEMP_PER_BLOCK / THREADS; ++it) {
            const int i = tb * TEMP_PER_BLOCK + it * THREADS + tid;
            const int b = i / ((S - 1) * N);
            const int r = i % ((S - 1) * N);
            const float* p0 = pred + (size_t)(b * S * N + r) * 3;
            const float* p1 = p0 + (size_t)N * 3;
            const float dx = p1[0] - p0[0];
            const float dy = p1[1] - p0[1];
            const float dz = p1[2] - p0[2];
            s += sqrtf(dx * dx + dy * dy + dz * dz);
        }
        const float tot = block_sum(s, red);
        if (tid == 0) ws[WS_TPART + tb] = tot;
    } else {
        float s = 0.0f;
        for (int it = 0; it < KL_ELEMS / THREADS; ++it) {
            const int i = it * THREADS + tid;
            const float a  = prior_lv[i];
            const float bb = post_lv[i];
            const float dm = post_mean[i] - prior_mean[i];
            s += a - bb + (expf(bb) + dm * dm) * expf(-a) - 1.0f;
        }
        const float tot = block_sum(s, red);
        if (tid == 0) ws[WS_KL] = tot;
    }
}

// ---------------------------------------------------------------------------
// K2: per-query min over KS slices, sqrt, per-block sum (640 blocks x 256 q)
// ---------------------------------------------------------------------------
__global__ __launch_bounds__(THREADS) void k2_kernel(float* __restrict__ ws) {
    __shared__ float red[2];
    float ssum = 0.0f;
    #pragma unroll
    for (int r = 0; r < 2; ++r) {
        const int u = blockIdx.x * 256 + r * THREADS + threadIdx.x;  // 640*256 = TOTQ
        float d2 = ws[u];
        #pragma unroll
        for (int k = 1; k < KS; ++k)
            d2 = fminf(d2, ws[(size_t)k * TOTQ + u]);
        ssum += sqrtf(fmaxf(d2, 0.0f));
    }
    const float tot = block_sum(ssum, red);
    if (threadIdx.x == 0) ws[WS_CHSUM + blockIdx.x] = tot;
}

// ---------------------------------------------------------------------------
// K3: final combine
// ---------------------------------------------------------------------------
__global__ __launch_bounds__(THREADS) void k3_kernel(const float* __restrict__ ws,
                                                     float* __restrict__ out) {
    __shared__ float red[2];
    float s = 0.0f;
    for (int i = threadIdx.x; i < CHAM_BLOCKS; i += THREADS)
        s += ws[WS_CHSUM + i];
    const float tot = block_sum(s, red);
    if (threadIdx.x == 0) {
        float tsum = 0.0f;
        for (int i = 0; i < TEMP_BLOCKS; ++i) tsum += ws[WS_TPART + i];
        const float recon    = tot / (float)(B * S * N);
        const float kl       = 0.5f * ws[WS_KL] / (float)(B * S);
        const float temporal = tsum / (float)TEMP_ELEMS;
        out[0] = recon + kl + 0.1f * temporal;
        out[1] = recon;
        out[2] = kl;
        out[3] = temporal;
        out[4] = 0.0f;
    }
}

extern "C" void kernel_launch(void* const* d_in, const int* in_sizes, int n_in,
                              void* d_out, int out_size, void* d_ws, size_t ws_size,
                              hipStream_t stream) {
    const float* pred = (const float*)d_in[0];
    const float* tgt  = (const float*)d_in[1];
    const float* pm   = (const float*)d_in[2];
    const float* plv  = (const float*)d_in[3];
    const float* qm   = (const float*)d_in[4];
    const float* qlv  = (const float*)d_in[5];
    float* out = (float*)d_out;
    float* ws  = (float*)d_ws;

    k1_kernel<<<TOTAL_BLOCKS, THREADS, 0, stream>>>(pred, tgt, pm, plv, qm, qlv, ws);
    k2_kernel<<<TOTQ / 256, THREADS, 0, stream>>>(ws);
    k3_kernel<<<1, THREADS, 0, stream>>>(ws, out);
}

// Round 6
// 122.975 us; speedup vs baseline: 1.8718x; 1.0036x over previous
//
#include <hip/hip_runtime.h>
#include <hip/hip_fp16.h>
#include <math.h>

// Problem constants (from reference setup_inputs)
constexpr int B = 4, S = 10, N = 2048, D = 128;

constexpr int THREADS = 128;            // 2 waves per block
constexpr int QPT     = N / THREADS;    // 16 queries per thread (all N per block)
constexpr int TEMP_BLOCKS = 16;
constexpr int TOTQ    = B * S * 2 * N;        // 163840 (query, dir) pairs
constexpr int TEMP_ELEMS = B * (S - 1) * N;   // 73728
constexpr int TEMP_PER_BLOCK = TEMP_ELEMS / TEMP_BLOCKS;  // 4608 = 36*128
constexpr int KL_ELEMS = B * S * D;           // 5120 = 40*128

// ws layout: [0 .. KS*TOTQ) __half d^2 partials, then float ctl block:
//   [0]=chamsum (atomic), [1]=ticket (uint), [2..18)=temporal sums, [18]=kl
constexpr int CTL_CHAM = 0, CTL_TICKET = 1, CTL_TPART = 2, CTL_KL = 18;

typedef float v2f __attribute__((ext_vector_type(2)));

// all operands are 64-bit pairs — compiles on gfx950 (verified R2/R4)
__device__ __forceinline__ v2f pk_fma(v2f a, v2f b, v2f c) {
    v2f d;
    asm("v_pk_fma_f32 %0, %1, %2, %3" : "=v"(d) : "v"(a), "v"(b), "v"(c));
    return d;
}

// result valid on thread 0 (128-thread block, 2 waves)
__device__ __forceinline__ float block_sum(float v, float* red) {
    #pragma unroll
    for (int off = 32; off > 0; off >>= 1)
        v += __shfl_down(v, off, 64);
    if ((threadIdx.x & 63) == 0) red[threadIdx.x >> 6] = v;
    __syncthreads();
    return red[0] + red[1];
}

// ---------------------------------------------------------------------------
// K1: [0, CHAM): chamfer d^2 partials (fp16); +16 temporal; +1 kl; +1 zeroer
// ---------------------------------------------------------------------------
template <int KSV>
__global__ __launch_bounds__(THREADS) void k1_kernel(
        const float* __restrict__ pred, const float* __restrict__ tgt,
        const float* __restrict__ prior_mean, const float* __restrict__ prior_lv,
        const float* __restrict__ post_mean,  const float* __restrict__ post_lv,
        __half* __restrict__ partH, float* __restrict__ ctl) {
    constexpr int SLICE = N / KSV;
    constexpr int CHAM  = B * S * 2 * KSV;
    __shared__ float4 db[SLICE];   // [2p]={x0,x1,y0,y1} [2p+1]={z0,z1,m0,m1}, m=-0.5|g|^2
    __shared__ float red[2];

    const int bid = blockIdx.x;
    const int tid = threadIdx.x;

    if (bid < CHAM) {
        const int ks  = bid % KSV;
        const int dir = (bid / KSV) & 1;
        const int bs  = bid / (2 * KSV);          // b*S + s, 0..39
        const float* qb  = (dir ? tgt : pred) + (size_t)bs * N * 3;  // queries
        const float* dbp = (dir ? pred : tgt) + (size_t)bs * N * 3;  // database

        // stage SLICE db points (1 pair per thread), pair-interleaved
        if (tid < SLICE / 2) {
            const int p0 = ks * SLICE + 2 * tid;
            const float x0 = dbp[3 * p0 + 0], y0 = dbp[3 * p0 + 1], z0 = dbp[3 * p0 + 2];
            const float x1 = dbp[3 * p0 + 3], y1 = dbp[3 * p0 + 4], z1 = dbp[3 * p0 + 5];
            db[2 * tid + 0] = make_float4(x0, x1, y0, y1);
            db[2 * tid + 1] = make_float4(z0, z1,
                                          -0.5f * (x0 * x0 + y0 * y0 + z0 * z0),
                                          -0.5f * (x1 * x1 + y1 * y1 + z1 * z1));
        }

        // 16 queries per thread, splatted for packed fma
        v2f px2[QPT], py2[QPT], pz2[QPT];
        float acc[QPT];
        #pragma unroll
        for (int i = 0; i < QPT; ++i) {
            const int q = tid + THREADS * i;
            const float x = qb[3 * q + 0], y = qb[3 * q + 1], z = qb[3 * q + 2];
            px2[i] = (v2f){x, x};
            py2[i] = (v2f){y, y};
            pz2[i] = (v2f){z, z};
            acc[i] = -1e30f;
        }
        __syncthreads();

        // max over slice of score = p.g - 0.5|g|^2 (2 db points per packed op)
        #pragma unroll 2
        for (int p = 0; p < SLICE / 2; ++p) {
            const float4 A = db[2 * p + 0];
            const float4 Z = db[2 * p + 1];
            const v2f xp = (v2f){A.x, A.y};
            const v2f yp = (v2f){A.z, A.w};
            const v2f zp = (v2f){Z.x, Z.y};
            const v2f mp = (v2f){Z.z, Z.w};
            #pragma unroll
            for (int i = 0; i < QPT; ++i) {
                v2f t = pk_fma(pz2[i], zp, mp);
                t = pk_fma(py2[i], yp, t);
                t = pk_fma(px2[i], xp, t);
                acc[i] = fmaxf(acc[i], fmaxf(t.x, t.y));   // v_max3_f32
            }
        }

        // partial d^2 for this slice -> fp16
        __half* part = partH + (size_t)ks * TOTQ + (size_t)(bs * 2 + dir) * N;
        #pragma unroll
        for (int i = 0; i < QPT; ++i) {
            const float x = px2[i].x, y = py2[i].x, z = pz2[i].x;
            const float pn = x * x + y * y + z * z;
            const float d2 = fmaxf(pn - 2.0f * acc[i], 0.0f);
            part[tid + THREADS * i] = __float2half(d2);
        }
    } else if (bid < CHAM + TEMP_BLOCKS) {
        const int tb = bid - CHAM;
        float s = 0.0f;
        for (int it = 0; it < TEMP_PER_BLOCK / THREADS; ++it) {
            const int i = tb * TEMP_PER_BLOCK + it * THREADS + tid;
            const int b = i / ((S - 1) * N);
            const int r = i % ((S - 1) * N);
            const float* p0 = pred + (size_t)(b * S * N + r) * 3;
            const float* p1 = p0 + (size_t)N * 3;
            const float dx = p1[0] - p0[0];
            const float dy = p1[1] - p0[1];
            const float dz = p1[2] - p0[2];
            s += sqrtf(dx * dx + dy * dy + dz * dz);
        }
        const float tot = block_sum(s, red);
        if (tid == 0) ctl[CTL_TPART + tb] = tot;
    } else if (bid == CHAM + TEMP_BLOCKS) {
        float s = 0.0f;
        for (int it = 0; it < KL_ELEMS / THREADS; ++it) {
            const int i = it * THREADS + tid;
            const float a  = prior_lv[i];
            const float bb = post_lv[i];
            const float dm = post_mean[i] - prior_mean[i];
            s += a - bb + (expf(bb) + dm * dm) * expf(-a) - 1.0f;
        }
        const float tot = block_sum(s, red);
        if (tid == 0) ctl[CTL_KL] = tot;
    } else {
        // zero k2's accumulator + ticket (consumed only after this dispatch)
        if (tid == 0) {
            ctl[CTL_CHAM] = 0.0f;
            ((unsigned*)ctl)[CTL_TICKET] = 0u;
        }
    }
}

// ---------------------------------------------------------------------------
// K2: per-query min over KSV slices, sqrt, block sum -> atomic chamsum;
//     last-ticket block writes the 5 outputs. 640 blocks x 128 (2 q/thread).
// ---------------------------------------------------------------------------
template <int KSV>
__global__ __launch_bounds__(THREADS) void k2_kernel(
        const __half* __restrict__ partH, float* __restrict__ ctl,
        float* __restrict__ out) {
    __shared__ float red[2];
    const int base = blockIdx.x * 256;
    const int t = threadIdx.x;

    float m0 = 1e30f, m1 = 1e30f;
    #pragma unroll
    for (int k = 0; k < KSV; ++k) {
        const __half2 h = *(const __half2*)(partH + (size_t)k * TOTQ + base + 2 * t);
        m0 = fminf(m0, __half2float(h.x));
        m1 = fminf(m1, __half2float(h.y));
    }
    const float s = sqrtf(m0) + sqrtf(m1);
    const float tot = block_sum(s, red);

    if (t == 0) {
        atomicAdd(&ctl[CTL_CHAM], tot);
        __threadfence();
        const unsigned ticket = atomicAdd(&((unsigned*)ctl)[CTL_TICKET], 1u);
        if (ticket == (unsigned)(TOTQ / 256 - 1)) {
            const float chamsum = __hip_atomic_load(&ctl[CTL_CHAM], __ATOMIC_ACQUIRE,
                                                    __HIP_MEMORY_SCOPE_AGENT);
            float tsum = 0.0f;
            for (int i = 0; i < TEMP_BLOCKS; ++i) tsum += ctl[CTL_TPART + i];
            const float recon    = chamsum / (float)(B * S * N);
            const float kl       = 0.5f * ctl[CTL_KL] / (float)(B * S);
            const float temporal = tsum / (float)TEMP_ELEMS;
            out[0] = recon + kl + 0.1f * temporal;
            out[1] = recon;
            out[2] = kl;
            out[3] = temporal;
            out[4] = 0.0f;
        }
    }
}

template <int KSV>
static void launch_all(const float* pred, const float* tgt,
                       const float* pm, const float* plv,
                       const float* qm, const float* qlv,
                       void* d_ws, float* out, hipStream_t stream) {
    __half* partH = (__half*)d_ws;
    float* ctl = (float*)d_ws + (size_t)KSV * TOTQ / 2;
    const int grid1 = B * S * 2 * KSV + TEMP_BLOCKS + 2;
    k1_kernel<KSV><<<grid1, THREADS, 0, stream>>>(pred, tgt, pm, plv, qm, qlv, partH, ctl);
    k2_kernel<KSV><<<TOTQ / 256, THREADS, 0, stream>>>(partH, ctl, out);
}

extern "C" void kernel_launch(void* const* d_in, const int* in_sizes, int n_in,
                              void* d_out, int out_size, void* d_ws, size_t ws_size,
                              hipStream_t stream) {
    const float* pred = (const float*)d_in[0];
    const float* tgt  = (const float*)d_in[1];
    const float* pm   = (const float*)d_in[2];
    const float* plv  = (const float*)d_in[3];
    const float* qm   = (const float*)d_in[4];
    const float* qlv  = (const float*)d_in[5];
    float* out = (float*)d_out;

    const size_t need32 = (size_t)32 * TOTQ * sizeof(__half) + 64 * sizeof(float);
    if (ws_size >= need32)
        launch_all<32>(pred, tgt, pm, plv, qm, qlv, d_ws, out, stream);
    else
        launch_all<8>(pred, tgt, pm, plv, qm, qlv, d_ws, out, stream);
}

// Round 7
// 114.835 us; speedup vs baseline: 2.0045x; 1.0709x over previous
//
#include <hip/hip_runtime.h>
#include <hip/hip_fp16.h>
#include <math.h>

// Problem constants (from reference setup_inputs)
constexpr int B = 4, S = 10, N = 2048, D = 128;

constexpr int THREADS = 128;            // 2 waves per block
constexpr int QPT     = N / THREADS;    // 16 queries per thread (all N per block)
constexpr int TEMP_BLOCKS = 16;
constexpr int TOTQ    = B * S * 2 * N;        // 163840 (query, dir) pairs
constexpr int TEMP_ELEMS = B * (S - 1) * N;   // 73728
constexpr int TEMP_PER_BLOCK = TEMP_ELEMS / TEMP_BLOCKS;  // 4608 = 36*128
constexpr int KL_ELEMS = B * S * D;           // 5120 = 40*128

// ws layout: [0 .. KS*TOTQ) __half d^2 partials, then float ctl block:
//   [0]=chamsum (atomic), [1]=ticket (uint), [2..18)=temporal sums, [18]=kl
constexpr int CTL_CHAM = 0, CTL_TICKET = 1, CTL_TPART = 2, CTL_KL = 18;

// result valid on thread 0 (128-thread block, 2 waves)
__device__ __forceinline__ float block_sum(float v, float* red) {
    #pragma unroll
    for (int off = 32; off > 0; off >>= 1)
        v += __shfl_down(v, off, 64);
    if ((threadIdx.x & 63) == 0) red[threadIdx.x >> 6] = v;
    __syncthreads();
    return red[0] + red[1];
}

// ---------------------------------------------------------------------------
// K1: [0, CHAM): chamfer d^2 partials (fp16); +16 temporal; +1 kl; +1 zeroer
// Inner loop: SCALAR v_fma chains (v_pk_fma_f32 is HALF scalar FLOP rate on
// gfx950 — measured R6: VALUBusy*dur matched 8 cyc/wave pk_fma exactly).
// 2 db points folded per v_max3_f32 -> 7 cyc/pair floor.
// ---------------------------------------------------------------------------
template <int KSV>
__global__ __launch_bounds__(THREADS) void k1_kernel(
        const float* __restrict__ pred, const float* __restrict__ tgt,
        const float* __restrict__ prior_mean, const float* __restrict__ prior_lv,
        const float* __restrict__ post_mean,  const float* __restrict__ post_lv,
        __half* __restrict__ partH, float* __restrict__ ctl) {
    constexpr int SLICE = N / KSV;
    constexpr int CHAM  = B * S * 2 * KSV;
    __shared__ float4 db[SLICE];   // (x, y, z, m) with m = -0.5*|g|^2
    __shared__ float red[2];

    const int bid = blockIdx.x;
    const int tid = threadIdx.x;

    if (bid < CHAM) {
        const int ks  = bid % KSV;
        const int dir = (bid / KSV) & 1;
        const int bs  = bid / (2 * KSV);          // b*S + s, 0..39
        const float* qb  = (dir ? tgt : pred) + (size_t)bs * N * 3;  // queries
        const float* dbp = (dir ? pred : tgt) + (size_t)bs * N * 3;  // database

        // stage SLICE db points (1 per thread)
        if (tid < SLICE) {
            const int p0 = ks * SLICE + tid;
            const float x = dbp[3 * p0 + 0], y = dbp[3 * p0 + 1], z = dbp[3 * p0 + 2];
            db[tid] = make_float4(x, y, z, -0.5f * (x * x + y * y + z * z));
        }

        // 16 queries per thread, plain scalars
        float qx[QPT], qy[QPT], qz[QPT], acc[QPT];
        #pragma unroll
        for (int i = 0; i < QPT; ++i) {
            const int q = tid + THREADS * i;
            qx[i] = qb[3 * q + 0];
            qy[i] = qb[3 * q + 1];
            qz[i] = qb[3 * q + 2];
            acc[i] = -1e30f;
        }
        __syncthreads();

        // max over slice of score = p.g - 0.5|g|^2; 2 points per max3 fold
        #pragma unroll 2
        for (int p = 0; p < SLICE; p += 2) {
            const float4 g0 = db[p + 0];
            const float4 g1 = db[p + 1];
            #pragma unroll
            for (int i = 0; i < QPT; ++i) {
                const float s0 = fmaf(qz[i], g0.z, fmaf(qy[i], g0.y, fmaf(qx[i], g0.x, g0.w)));
                const float s1 = fmaf(qz[i], g1.z, fmaf(qy[i], g1.y, fmaf(qx[i], g1.x, g1.w)));
                acc[i] = fmaxf(acc[i], fmaxf(s0, s1));   // v_max3_f32
            }
        }

        // partial d^2 for this slice -> fp16
        __half* part = partH + (size_t)ks * TOTQ + (size_t)(bs * 2 + dir) * N;
        #pragma unroll
        for (int i = 0; i < QPT; ++i) {
            const float pn = qx[i] * qx[i] + qy[i] * qy[i] + qz[i] * qz[i];
            const float d2 = fmaxf(pn - 2.0f * acc[i], 0.0f);
            part[tid + THREADS * i] = __float2half(d2);
        }
    } else if (bid < CHAM + TEMP_BLOCKS) {
        const int tb = bid - CHAM;
        float s = 0.0f;
        for (int it = 0; it < TEMP_PER_BLOCK / THREADS; ++it) {
            const int i = tb * TEMP_PER_BLOCK + it * THREADS + tid;
            const int b = i / ((S - 1) * N);
            const int r = i % ((S - 1) * N);
            const float* p0 = pred + (size_t)(b * S * N + r) * 3;
            const float* p1 = p0 + (size_t)N * 3;
            const float dx = p1[0] - p0[0];
            const float dy = p1[1] - p0[1];
            const float dz = p1[2] - p0[2];
            s += sqrtf(dx * dx + dy * dy + dz * dz);
        }
        const float tot = block_sum(s, red);
        if (tid == 0) ctl[CTL_TPART + tb] = tot;
    } else if (bid == CHAM + TEMP_BLOCKS) {
        float s = 0.0f;
        for (int it = 0; it < KL_ELEMS / THREADS; ++it) {
            const int i = it * THREADS + tid;
            const float a  = prior_lv[i];
            const float bb = post_lv[i];
            const float dm = post_mean[i] - prior_mean[i];
            s += a - bb + (expf(bb) + dm * dm) * expf(-a) - 1.0f;
        }
        const float tot = block_sum(s, red);
        if (tid == 0) ctl[CTL_KL] = tot;
    } else {
        // zero k2's accumulator + ticket (consumed only after this dispatch)
        if (tid == 0) {
            ctl[CTL_CHAM] = 0.0f;
            ((unsigned*)ctl)[CTL_TICKET] = 0u;
        }
    }
}

// ---------------------------------------------------------------------------
// K2: per-query min over KSV slices, sqrt, block sum -> atomic chamsum;
//     last-ticket block writes the 5 outputs. 640 blocks x 128 (2 q/thread).
// ---------------------------------------------------------------------------
template <int KSV>
__global__ __launch_bounds__(THREADS) void k2_kernel(
        const __half* __restrict__ partH, float* __restrict__ ctl,
        float* __restrict__ out) {
    __shared__ float red[2];
    const int base = blockIdx.x * 256;
    const int t = threadIdx.x;

    float m0 = 1e30f, m1 = 1e30f;
    #pragma unroll
    for (int k = 0; k < KSV; ++k) {
        const __half2 h = *(const __half2*)(partH + (size_t)k * TOTQ + base + 2 * t);
        m0 = fminf(m0, __half2float(h.x));
        m1 = fminf(m1, __half2float(h.y));
    }
    const float s = sqrtf(m0) + sqrtf(m1);
    const float tot = block_sum(s, red);

    if (t == 0) {
        atomicAdd(&ctl[CTL_CHAM], tot);
        __threadfence();
        const unsigned ticket = atomicAdd(&((unsigned*)ctl)[CTL_TICKET], 1u);
        if (ticket == (unsigned)(TOTQ / 256 - 1)) {
            const float chamsum = __hip_atomic_load(&ctl[CTL_CHAM], __ATOMIC_ACQUIRE,
                                                    __HIP_MEMORY_SCOPE_AGENT);
            float tsum = 0.0f;
            for (int i = 0; i < TEMP_BLOCKS; ++i) tsum += ctl[CTL_TPART + i];
            const float recon    = chamsum / (float)(B * S * N);
            const float kl       = 0.5f * ctl[CTL_KL] / (float)(B * S);
            const float temporal = tsum / (float)TEMP_ELEMS;
            out[0] = recon + kl + 0.1f * temporal;
            out[1] = recon;
            out[2] = kl;
            out[3] = temporal;
            out[4] = 0.0f;
        }
    }
}

template <int KSV>
static void launch_all(const float* pred, const float* tgt,
                       const float* pm, const float* plv,
                       const float* qm, const float* qlv,
                       void* d_ws, float* out, hipStream_t stream) {
    __half* partH = (__half*)d_ws;
    float* ctl = (float*)d_ws + (size_t)KSV * TOTQ / 2;
    const int grid1 = B * S * 2 * KSV + TEMP_BLOCKS + 2;
    k1_kernel<KSV><<<grid1, THREADS, 0, stream>>>(pred, tgt, pm, plv, qm, qlv, partH, ctl);
    k2_kernel<KSV><<<TOTQ / 256, THREADS, 0, stream>>>(partH, ctl, out);
}

extern "C" void kernel_launch(void* const* d_in, const int* in_sizes, int n_in,
                              void* d_out, int out_size, void* d_ws, size_t ws_size,
                              hipStream_t stream) {
    const float* pred = (const float*)d_in[0];
    const float* tgt  = (const float*)d_in[1];
    const float* pm   = (const float*)d_in[2];
    const float* plv  = (const float*)d_in[3];
    const float* qm   = (const float*)d_in[4];
    const float* qlv  = (const float*)d_in[5];
    float* out = (float*)d_out;

    const size_t need32 = (size_t)32 * TOTQ * sizeof(__half) + 64 * sizeof(float);
    if (ws_size >= need32)
        launch_all<32>(pred, tgt, pm, plv, qm, qlv, d_ws, out, stream);
    else
        launch_all<8>(pred, tgt, pm, plv, qm, qlv, d_ws, out, stream);
}